// Round 1
// baseline (75.235 us; speedup 1.0000x reference)
//
#include <hip/hip_runtime.h>

// Shapes fixed by the reference: bs=4, n=10, H=W=256.
constexpr int kN   = 10;      // planes
constexpr int kHW  = 256 * 256;
constexpr int kBS  = 4;

// One thread handles 4 consecutive pixels (float4 loads/stores).
// Arithmetic deliberately mirrors numpy's std(ddof=1) evaluation order:
// sequential sum over j, true division by 10, (v-mean)*(v-mean) with NO fma
// contraction, sequential sum, true division by 9, IEEE sqrt.
__global__ __launch_bounds__(256) void distreg_kernel(
    const float* __restrict__ s1, const float* __restrict__ blur,
    float* __restrict__ out) {
  #pragma clang fp contract(off)
  const int g = blockIdx.x * blockDim.x + threadIdx.x;  // group of 4 pixels
  constexpr int groups_per_img = kHW / 4;
  const int b = g / groups_per_img;
  const int r = g - b * groups_per_img;

  const long base = (long)b * kN * kHW + (long)r * 4;

  float4 s1v[kN], blv[kN];
  #pragma unroll
  for (int j = 0; j < kN; ++j) {
    s1v[j] = *(const float4*)(s1 + base + (long)j * kHW);
    blv[j] = *(const float4*)(blur + base + (long)j * kHW);
  }

  float res[4];
  #pragma unroll
  for (int k = 0; k < 4; ++k) {
    float lo[kN], hi[kN];
    #pragma unroll
    for (int j = 0; j < kN; ++j) {
      const float s  = ((const float*)&s1v[j])[k];
      const float bl = ((const float*)&blv[j])[k];
      lo[j] = s - bl;   // used for j >= split i
      hi[j] = s + bl;   // used for j <  split i
    }

    float best_std = INFINITY;
    int   best_i   = 0;
    #pragma unroll
    for (int i = 0; i <= kN; ++i) {
      float sum = 0.0f;
      #pragma unroll
      for (int j = 0; j < kN; ++j) sum = sum + ((j < i) ? hi[j] : lo[j]);
      const float mean = sum / 10.0f;

      float sq = 0.0f;
      #pragma unroll
      for (int j = 0; j < kN; ++j) {
        const float x  = ((j < i) ? hi[j] : lo[j]) - mean;
        const float xx = x * x;     // contract(off): stays a separate mul
        sq = sq + xx;
      }
      const float var = sq / 9.0f;
      const float sd  = sqrtf(var);  // HIP default: correctly-rounded fp32 sqrt
      if (sd < best_std) { best_std = sd; best_i = i; }  // first-occurrence argmin
    }

    float sum = 0.0f;
    #pragma unroll
    for (int j = 0; j < kN; ++j) sum = sum + ((j < best_i) ? hi[j] : lo[j]);
    res[k] = sum / 10.0f;
  }

  const long ob = (long)b * kHW + (long)r * 4;
  *(float4*)(out + ob) = make_float4(res[0], res[1], res[2], res[3]);
}

extern "C" void kernel_launch(void* const* d_in, const int* in_sizes, int n_in,
                              void* d_out, int out_size, void* d_ws, size_t ws_size,
                              hipStream_t stream) {
  const float* s1   = (const float*)d_in[0];
  const float* blur = (const float*)d_in[1];
  float* out = (float*)d_out;

  const int total_groups = kBS * kHW / 4;  // 65536 threads
  const int block = 256;
  const int grid = total_groups / block;   // 256 blocks
  distreg_kernel<<<grid, block, 0, stream>>>(s1, blur, out);
}

// Round 2
// 73.143 us; speedup vs baseline: 1.0286x; 1.0286x over previous
//
#include <hip/hip_runtime.h>

// Shapes fixed by the reference: bs=4, n=10, H=W=256.
constexpr int kN  = 10;        // planes
constexpr int kHW = 256 * 256;
constexpr int kBS = 4;

// One thread per pixel. Per-lane scalar loads are fully coalesced
// (64 lanes x 4 B = 256 B per wave-load). 1,048,576 threads = 4096 blocks
// = 4 waves/SIMD for latency hiding (R1 had only 1 wave/SIMD).
//
// Arithmetic deliberately mirrors numpy's std(ddof=1) evaluation order
// (bit-exact in R1: absmax 0.0): sequential sum over j, true division by 10,
// (v-mean)*(v-mean) with NO fma contraction, sequential sum, true division
// by 9, IEEE sqrt, strict < first-occurrence argmin. DO NOT "optimize" the
// math: incremental-sum recurrences or var-based argmin can flip ties and
// cost up to 2*blur/n ~ 0.2 per flipped pixel vs threshold 3.8e-2.
__global__ __launch_bounds__(256) void distreg_kernel(
    const float* __restrict__ s1, const float* __restrict__ blur,
    float* __restrict__ out) {
  #pragma clang fp contract(off)
  const int g = blockIdx.x * blockDim.x + threadIdx.x;  // pixel id
  const int b = g / kHW;
  const int r = g - b * kHW;

  const long base = (long)b * kN * kHW + r;

  float lo[kN], hi[kN];
  #pragma unroll
  for (int j = 0; j < kN; ++j) {
    const float s  = s1[base + (long)j * kHW];
    const float bl = blur[base + (long)j * kHW];
    lo[j] = s - bl;   // used for j >= split i
    hi[j] = s + bl;   // used for j <  split i
  }

  float best_std = INFINITY;
  int   best_i   = 0;
  #pragma unroll
  for (int i = 0; i <= kN; ++i) {
    float sum = 0.0f;
    #pragma unroll
    for (int j = 0; j < kN; ++j) sum = sum + ((j < i) ? hi[j] : lo[j]);
    const float mean = sum / 10.0f;

    float sq = 0.0f;
    #pragma unroll
    for (int j = 0; j < kN; ++j) {
      const float x  = ((j < i) ? hi[j] : lo[j]) - mean;
      const float xx = x * x;     // contract(off): stays a separate mul
      sq = sq + xx;
    }
    const float var = sq / 9.0f;
    const float sd  = sqrtf(var);  // IEEE-correct fp32 sqrt (no fast-math)
    if (sd < best_std) { best_std = sd; best_i = i; }  // first occurrence
  }

  float sum = 0.0f;
  #pragma unroll
  for (int j = 0; j < kN; ++j) sum = sum + ((j < best_i) ? hi[j] : lo[j]);

  out[(long)b * kHW + r] = sum / 10.0f;
}

extern "C" void kernel_launch(void* const* d_in, const int* in_sizes, int n_in,
                              void* d_out, int out_size, void* d_ws, size_t ws_size,
                              hipStream_t stream) {
  const float* s1   = (const float*)d_in[0];
  const float* blur = (const float*)d_in[1];
  float* out = (float*)d_out;

  const int total = kBS * kHW;            // 1,048,576 pixels
  const int block = 256;
  const int grid  = total / block;        // 4096 blocks
  distreg_kernel<<<grid, block, 0, stream>>>(s1, blur, out);
}

// Round 3
// 70.231 us; speedup vs baseline: 1.0713x; 1.0415x over previous
//
#include <hip/hip_runtime.h>

// Shapes fixed by the reference: bs=4, n=10, H=W=256.
constexpr int kN  = 10;        // planes
constexpr int kHW = 256 * 256;
constexpr int kBS = 4;

// One thread per pixel; per-lane scalar loads are fully coalesced.
//
// Bit-exactness contract (absmax == 0.0 in R1/R2 — preserve it):
//  * sum over planes: left-associative sequential adds (prefix-shared here,
//    SAME association as the reference fold).
//  * x/10 and x/9: implemented as (float)((double)x * RN(1/10 or 1/9)).
//    Proven identical to correctly-rounded fp32 division for all inputs:
//    f64 product rel-err <= 2.3e-16, while m*2^e/10 (resp /9) is never
//    closer than ~1.5e-9 (resp ~8e-10) rel. to an fp32 rounding midpoint
//    (integer divisibility: 10(2k+1) == 2 mod 4 vs 16m; 9(2k+1) odd).
//  * (v-mean)^2: separate sub/mul/add under fp contract(off) — no FMA.
//  * sqrtf: HIP default correctly-rounded fp32 sqrt.
//  * argmin: strict <, first occurrence.
// DO NOT introduce incremental-sum recurrences, var-based argmin, or FMA
// contraction: an argmin tie-flip costs up to 2*blur/n ~ 0.2 vs thr 3.8e-2.
__global__ __launch_bounds__(256) void distreg_kernel(
    const float* __restrict__ s1, const float* __restrict__ blur,
    float* __restrict__ out) {
  #pragma clang fp contract(off)
  const int g = blockIdx.x * blockDim.x + threadIdx.x;  // pixel id
  const int b = g >> 16;        // kHW == 65536
  const int r = g & (kHW - 1);

  const long base = (long)b * kN * kHW + r;

  float lo[kN], hi[kN];
  #pragma unroll
  for (int j = 0; j < kN; ++j) {
    const float s  = s1[base + (long)j * kHW];
    const float bl = blur[base + (long)j * kHW];
    lo[j] = s - bl;   // used for j >= split i
    hi[j] = s + bl;   // used for j <  split i
  }

  float best_sd   = INFINITY;
  float best_mean = 0.0f;
  float p = 0.0f;               // prefix: hi[0] + ... + hi[i-1], left-assoc
  #pragma unroll
  for (int i = 0; i <= kN; ++i) {
    // sum_i = ((p + lo[i]) + lo[i+1]) + ... — same association as reference.
    float sum = p;
    #pragma unroll
    for (int j = 0; j < kN; ++j) if (j >= i) sum = sum + lo[j];
    const float mean = (float)((double)sum * 0.1);      // == sum / 10.0f

    float sq = 0.0f;
    #pragma unroll
    for (int j = 0; j < kN; ++j) {
      const float v  = (j < i) ? hi[j] : lo[j];         // static select
      const float x  = v - mean;
      const float xx = x * x;    // contract(off): stays a separate mul
      sq = sq + xx;
    }
    const float var = (float)((double)sq * (1.0 / 9.0)); // == sq / 9.0f
    const float sd  = sqrtf(var);

    if (sd < best_sd) { best_sd = sd; best_mean = mean; } // first occurrence
    if (i < kN) p = p + hi[i];
  }

  out[(long)b * kHW + r] = best_mean;
}

extern "C" void kernel_launch(void* const* d_in, const int* in_sizes, int n_in,
                              void* d_out, int out_size, void* d_ws, size_t ws_size,
                              hipStream_t stream) {
  const float* s1   = (const float*)d_in[0];
  const float* blur = (const float*)d_in[1];
  float* out = (float*)d_out;

  const int total = kBS * kHW;            // 1,048,576 pixels
  const int block = 256;
  const int grid  = total / block;        // 4096 blocks
  distreg_kernel<<<grid, block, 0, stream>>>(s1, blur, out);
}